// Round 4
// baseline (204.458 us; speedup 1.0000x reference)
//
#include <hip/hip_runtime.h>
#include <hip/hip_bf16.h>

#define DIMF 128
#define KNBR 32
#define NH 4
#define DH 32
#define RADIUS 0.3f
#define CB 4       // centers per attn block
#define CAND 256   // max candidates/center (Poisson max lambda~118)
#define PPB 32     // points per argmin block (256 threads, 8 lanes/pt)
#define TMAIN 256

#define PACK_BLOCKS 60     // 4+4+4+16+16 float4-transposes + 16 Wk-pack

typedef unsigned long long u64t;

// float4-granular transpose tile: out4[a*BI + b] = in4[b*AI + a]
__device__ __forceinline__ void tr4_tile(const float4* __restrict__ in4, float4* __restrict__ out4,
                                         int AI, int BI, int a0, int b0, int t, char* smem) {
    float4(*tile)[33] = (float4(*)[33])smem;
    int tx = t & 31, ty = t >> 5;  // 32 x 8
    for (int r = ty; r < 32; r += 8) tile[r][tx] = in4[(long)(b0 + r) * AI + a0 + tx];
    __syncthreads();
    for (int r = ty; r < 32; r += 8) out4[(long)(a0 + r) * BI + b0 + tx] = tile[tx][r];
}

// ================= kernel 1: weight packs only (tiny, true dep of main) =====
__global__ __launch_bounds__(256) void pack_kernel(
    const float* __restrict__ Wq, const float* __restrict__ Wv,
    const float* __restrict__ Wo, const float* __restrict__ W1,
    const float* __restrict__ W2, const float* __restrict__ Wk,
    float4* __restrict__ qp4, float4* __restrict__ vp4, float4* __restrict__ op4,
    float4* __restrict__ w1p4, float4* __restrict__ w2p4, float4* __restrict__ kp4) {
    __shared__ __align__(16) char smem[16896];
    int pk = blockIdx.x, t = threadIdx.x;
    if (pk < 4) {
        tr4_tile((const float4*)Wq, qp4, 32, 128, 0, pk * 32, t, smem);
    } else if (pk < 8) {
        tr4_tile((const float4*)Wv, vp4, 32, 128, 0, (pk - 4) * 32, t, smem);
    } else if (pk < 12) {
        tr4_tile((const float4*)Wo, op4, 32, 128, 0, (pk - 8) * 32, t, smem);
    } else if (pk < 28) {
        tr4_tile((const float4*)W1, w1p4, 32, 512, 0, (pk - 12) * 32, t, smem);
    } else if (pk < 44) {
        int i = pk - 28;
        tr4_tile((const float4*)W2, w2p4, 128, 128, (i >> 2) * 32, (i & 3) * 32, t, smem);
    } else {
        // Wk pack: kp4[q*128+j] = {Wk[(4q+r)*128+j]}_{r=0..3}
        int idx = (pk - 44) * 256 + t;
        int q = idx >> 7, j = idx & 127;
        float4 w;
        w.x = Wk[(long)(4 * q + 0) * DIMF + j];
        w.y = Wk[(long)(4 * q + 1) * DIMF + j];
        w.z = Wk[(long)(4 * q + 2) * DIMF + j];
        w.w = Wk[(long)(4 * q + 3) * DIMF + j];
        kp4[q * DIMF + j] = w;
    }
}

// ================= kernel 2: main — CB=4, 256 threads/block ==================
// R3 post-mortem: more waves per barrier-domain didn't help (112 vs R1's 104us
// at equal VALUBusy~61%): stalls are correlated within a block (all waves wait
// at the same __syncthreads), so the lever is INDEPENDENT blocks per CU.
// CB=4 halves LDS to ~17KB: grid = 1024 attn + 512 argmin = 1536 blocks, all
// resident from t=0 (thread cap 8 blocks/CU), 6 barrier domains/CU sustained.
__global__ __launch_bounds__(256) void main_kernel(
    const float* __restrict__ xyz, const float* __restrict__ feats,
    const int* __restrict__ idxc,
    const float4* __restrict__ qp4, const float4* __restrict__ kp4,
    const float4* __restrict__ vp4, const float4* __restrict__ op4,
    const float* __restrict__ bo, const float* __restrict__ g1,
    const float* __restrict__ be1, const float* __restrict__ g2,
    const float* __restrict__ be2, const float4* __restrict__ w1p4,
    const float* __restrict__ b1f, const float4* __restrict__ w2p4,
    const float* __restrict__ b2f, float* __restrict__ cfin,
    int* __restrict__ bestm, int N, int M) {
    __shared__ __align__(16) char smem[16384];
    __shared__ int nbrl[CB][KNBR];
    __shared__ int cnt[CB];

    int t = threadIdx.x;
    int b = blockIdx.x;
    int nAttn = M / CB;

    if (b >= nAttn) {
        // ---------- nearest-center argmin, 32 pts/block, 8 lanes/pt ----------
        // Key: s = |c|^2 - 2 c.p (same argmin as d2; sqrt monotone). Exact-dup
        // centers give equal s -> lexicographic (s, index) min == np.argmin.
        float4* cds = (float4*)smem;
        int pt = t >> 3, q = t & 7;
        int n = (b - nAttn) * PPB + pt;
        float px = xyz[3 * n], py = xyz[3 * n + 1], pz = xyz[3 * n + 2];
        float bd0 = INFINITY, bd1 = INFINITY;
        int bm0 = 0, bm1 = 0;
        for (int c0 = 0; c0 < M; c0 += 1024) {
            __syncthreads();
            for (int i = t; i < 1024; i += TMAIN) {
                int ic = idxc[c0 + i];
                float cx = xyz[3 * ic], cy = xyz[3 * ic + 1], cz = xyz[3 * ic + 2];
                cds[i] = make_float4(-2.0f * cx, -2.0f * cy, -2.0f * cz,
                                     (cx * cx + cy * cy) + cz * cz);
            }
            __syncthreads();
#pragma unroll 8
            for (int i = 0; i < 64; ++i) {
                int ci0 = q + (2 * i) * 8, ci1 = q + (2 * i + 1) * 8;
                float4 ca = cds[ci0];
                float4 cb = cds[ci1];
                float sa = fmaf(ca.x, px, fmaf(ca.y, py, fmaf(ca.z, pz, ca.w)));
                float sb = fmaf(cb.x, px, fmaf(cb.y, py, fmaf(cb.z, pz, cb.w)));
                if (sa < bd0) { bd0 = sa; bm0 = c0 + ci0; }  // strict <: ascending scan keeps lowest idx
                if (sb < bd1) { bd1 = sb; bm1 = c0 + ci1; }
            }
        }
        if (bd1 < bd0 || (bd1 == bd0 && bm1 < bm0)) { bd0 = bd1; bm0 = bm1; }
#pragma unroll
        for (int o = 1; o < 8; o <<= 1) {
            float obd = __shfl_xor(bd0, o);
            int obm = __shfl_xor(bm0, o);
            if (obd < bd0 || (obd == bd0 && obm < bm0)) { bd0 = obd; bm0 = obm; }
        }
        if (q == 0) bestm[n] = bm0;
        return;
    }

    int m0 = b * CB;

    // ======== phase 1: radius top-K for centers m0..m0+3 ========
    {
        u64t(*cand)[CAND] = (u64t(*)[CAND])smem;
        if (t < CB) cnt[t] = 0;
        __syncthreads();
        float nx[CB], ny[CB], nz[CB], cw[CB];
#pragma unroll
        for (int tc = 0; tc < CB; ++tc) {
            int ic = idxc[m0 + tc];
            float cx = xyz[3 * ic], cy = xyz[3 * ic + 1], cz = xyz[3 * ic + 2];
            cw[tc] = (cx * cx + cy * cy) + cz * cz;
            nx[tc] = -2.0f * cx; ny[tc] = -2.0f * cy; nz[tc] = -2.0f * cz;
        }
        const float R2 = RADIUS * RADIUS;
        for (int n = t; n < N; n += TMAIN) {
            float x = xyz[3 * n], y = xyz[3 * n + 1], z = xyz[3 * n + 2];
            float pw = (x * x + y * y) + z * z;
            float rhs = R2 - pw;  // s < rhs  <=>  s + pw < R2
#pragma unroll
            for (int tc = 0; tc < CB; ++tc) {
                float s = fmaf(nx[tc], x, fmaf(ny[tc], y, fmaf(nz[tc], z, cw[tc])));
                if (s < rhs) {
                    int pos = atomicAdd(&cnt[tc], 1);
                    if (pos < CAND)
                        cand[tc][pos] = (((u64t)__float_as_uint(fmaxf(s + pw, 0.0f))) << 32) | (unsigned)n;
                }
            }
        }
        __syncthreads();
        // wave w extracts center w via rank-select into LDS nbrl (4 waves)
        int w = t >> 6, lane = t & 63;
        {
            int cidx = w;
            int C = cnt[cidx] < CAND ? cnt[cidx] : CAND;
            const u64t* vc = cand[cidx];
            if (C <= 64) {
                u64t mykey = (lane < C) ? vc[lane] : ~0ull;
                int rank = 0;
                for (int j = 0; j < C; ++j) rank += (vc[j] < mykey) ? 1 : 0;
                if (lane < C && rank < KNBR) nbrl[cidx][rank] = (int)(mykey & 0xffffffffu);
                if (lane >= C && lane < KNBR) nbrl[cidx][lane] = -1;
            } else {
                u64t mykey[4];
                int myrank[4];
#pragma unroll
                for (int s = 0; s < 4; ++s) {
                    int i = s * 64 + lane;
                    mykey[s] = (i < C) ? vc[i] : ~0ull;
                    myrank[s] = 0;
                }
                for (int j = 0; j < C; ++j) {
                    u64t kj = vc[j];
#pragma unroll
                    for (int s = 0; s < 4; ++s) myrank[s] += (kj < mykey[s]) ? 1 : 0;
                }
#pragma unroll
                for (int s = 0; s < 4; ++s) {
                    int i = s * 64 + lane;
                    if (i < C && myrank[s] < KNBR) nbrl[cidx][myrank[s]] = (int)(mykey[s] & 0xffffffffu);
                }
            }
        }
    }
    __syncthreads();  // cand reads done; smem becomes attn buffers

    // ======== phase 2: attention + FFN (CB=4 maps) ========
    float(*cf)[DIMF] = (float(*)[DIMF])smem;
    float(*cf2)[DIMF] = (float(*)[DIMF])(smem + 2048);
    float(*S1)[4 * DIMF] = (float(*)[4 * DIMF])(smem + 4096);
    float(*S2)[DIMF] = (float(*)[DIMF])(smem + 12288);
    float(*S3)[DIMF] = (float(*)[DIMF])(smem + 14336);

    if (t < 128) {
        int c4 = t >> 5, k32 = t & 31;
        int ic = idxc[m0 + c4];
        *(float4*)&cf[c4][k32 * 4] = *(const float4*)&feats[(long)ic * DIMF + k32 * 4];
    }
    __syncthreads();

    // ---- A: q = Wq @ cf (scaled) -> S2 ; 2 centers/thread ----
    {
        int i = t & 127, cpair = (t >> 7) * 2;
        float acc0 = 0.f, acc1 = 0.f;
        for (int jj = 0; jj < 32; ++jj) {
            float4 w = qp4[jj * DIMF + i];
            float4 x0 = *(const float4*)&cf[cpair][jj * 4];
            float4 x1 = *(const float4*)&cf[cpair + 1][jj * 4];
            acc0 += w.x * x0.x + w.y * x0.y + w.z * x0.z + w.w * x0.w;
            acc1 += w.x * x1.x + w.y * x1.y + w.z * x1.z + w.w * x1.w;
        }
        S2[cpair][i] = acc0 * 0.17677669529663687f;
        S2[cpair + 1][i] = acc1 * 0.17677669529663687f;
    }
    __syncthreads();

    // ---- B: qw[c][h][j] -> S1 ; 2 heads/thread, 4 centers ----
    {
        int j = t & 127, hbase = (t >> 7) * 2;
#pragma unroll
        for (int hh = 0; hh < 2; ++hh) {
            int h = hbase + hh;
            float acc[CB] = {0.f, 0.f, 0.f, 0.f};
            for (int d4 = 0; d4 < 8; ++d4) {
                float4 w = kp4[(h * 8 + d4) * DIMF + j];
#pragma unroll
                for (int c = 0; c < CB; ++c) {
                    float4 qv = *(const float4*)&S2[c][h * DH + d4 * 4];
                    acc[c] += qv.x * w.x + qv.y * w.y + qv.z * w.z + qv.w * w.w;
                }
            }
#pragma unroll
            for (int c = 0; c < CB; ++c) S1[c][h * DIMF + j] = acc[c];
        }
    }
    __syncthreads();

    // ---- C: logits + softmax -> S3 ; 64 lanes/center, 2 heads/thread ----
    {
        int c4 = t >> 6, hh = (t >> 5) & 1, k32 = t & 31;
        int h0 = hh * 2, h1 = hh * 2 + 1;
        int ni = nbrl[c4][k32];
        const float* nrow = feats + (long)(ni < 0 ? 0 : ni) * DIMF;
        float lg0 = 0.f, lg1 = 0.f;
        for (int jj = 0; jj < 32; ++jj) {
            float4 f = *(const float4*)&nrow[jj * 4];
            float4 qa = *(const float4*)&S1[c4][h0 * DIMF + jj * 4];
            float4 qb = *(const float4*)&S1[c4][h1 * DIMF + jj * 4];
            lg0 += f.x * qa.x + f.y * qa.y + f.z * qa.z + f.w * qa.w;
            lg1 += f.x * qb.x + f.y * qb.y + f.z * qb.z + f.w * qb.w;
        }
        if (ni < 0) { lg0 = -1e9f; lg1 = -1e9f; }
        {
            float mx = lg0;
            for (int o = 16; o; o >>= 1) mx = fmaxf(mx, __shfl_xor(mx, o, 32));
            float e = expf(lg0 - mx);
            float s = e;
            for (int o = 16; o; o >>= 1) s += __shfl_xor(s, o, 32);
            S3[c4][h0 * KNBR + k32] = e / s;
        }
        {
            float mx = lg1;
            for (int o = 16; o; o >>= 1) mx = fmaxf(mx, __shfl_xor(mx, o, 32));
            float e = expf(lg1 - mx);
            float s = e;
            for (int o = 16; o; o >>= 1) s += __shfl_xor(s, o, 32);
            S3[c4][h1 * KNBR + k32] = e / s;
        }
    }
    __syncthreads();

    // ---- D: pool -> S1 (overwrite qw) ; 64 lanes/center, 2 heads/thread ----
    {
        int c4 = t >> 6, hh = (t >> 5) & 1, j32 = t & 31;
        int j4 = j32 * 4;
        int h0 = hh * 2, h1 = hh * 2 + 1;
        float a0x = 0.f, a0y = 0.f, a0z = 0.f, a0w = 0.f;
        float a1x = 0.f, a1y = 0.f, a1z = 0.f, a1w = 0.f;
        for (int k = 0; k < KNBR; ++k) {
            int ni = nbrl[c4][k];
            const float* nrow = feats + (long)(ni < 0 ? 0 : ni) * DIMF;
            float4 f = *(const float4*)&nrow[j4];
            float w0 = S3[c4][h0 * KNBR + k], w1 = S3[c4][h1 * KNBR + k];
            a0x += w0 * f.x; a0y += w0 * f.y; a0z += w0 * f.z; a0w += w0 * f.w;
            a1x += w1 * f.x; a1y += w1 * f.y; a1z += w1 * f.z; a1w += w1 * f.w;
        }
        __syncthreads();
        *(float4*)&S1[c4][h0 * DIMF + j4] = make_float4(a0x, a0y, a0z, a0w);
        *(float4*)&S1[c4][h1 * DIMF + j4] = make_float4(a1x, a1y, a1z, a1w);
    }
    __syncthreads();

    // ---- E: updin -> S2 ; 2 centers/thread ----
    {
        int i = t & 127, cpair = (t >> 7) * 2;
        int h = i >> 5, d = i & 31;
        float acc0 = 0.f, acc1 = 0.f;
        for (int jj = 0; jj < 32; ++jj) {
            float4 w = vp4[jj * DIMF + i];
            float4 p0 = *(const float4*)&S1[cpair][h * DIMF + jj * 4];
            float4 p1 = *(const float4*)&S1[cpair + 1][h * DIMF + jj * 4];
            acc0 += w.x * p0.x + w.y * p0.y + w.z * p0.z + w.w * p0.w;
            acc1 += w.x * p1.x + w.y * p1.y + w.z * p1.z + w.w * p1.w;
        }
        __syncthreads();
        S2[cpair][d * NH + h] = acc0;
        S2[cpair + 1][d * NH + h] = acc1;
    }
    __syncthreads();

    // ---- F: upd = Wo @ updin + bo -> S3 ; 2 centers/thread ----
    {
        int i = t & 127, cpair = (t >> 7) * 2;
        float acc0 = 0.f, acc1 = 0.f;
        for (int jj = 0; jj < 32; ++jj) {
            float4 w = op4[jj * DIMF + i];
            float4 x0 = *(const float4*)&S2[cpair][jj * 4];
            float4 x1 = *(const float4*)&S2[cpair + 1][jj * 4];
            acc0 += w.x * x0.x + w.y * x0.y + w.z * x0.z + w.w * x0.w;
            acc1 += w.x * x1.x + w.y * x1.y + w.z * x1.z + w.w * x1.w;
        }
        float bb = bo[i];
        __syncthreads();
        S3[cpair][i] = acc0 + bb;
        S3[cpair + 1][i] = acc1 + bb;
    }
    __syncthreads();

    // ---- G: LN1 + residual -> cf2 (128-thread map) ----
    if (t < 128) {
        int c4 = t >> 5, k32 = t & 31;
        int i4 = k32 * 4;
        float4 u = *(const float4*)&S3[c4][i4];
        float s = ((u.x + u.y) + u.z) + u.w;
        for (int o = 16; o; o >>= 1) s += __shfl_xor(s, o, 32);
        float mu = s * (1.0f / DIMF);
        float d0 = u.x - mu, d1 = u.y - mu, d2 = u.z - mu, d3 = u.w - mu;
        float vs = ((d0 * d0 + d1 * d1) + d2 * d2) + d3 * d3;
        for (int o = 16; o; o >>= 1) vs += __shfl_xor(vs, o, 32);
        float rs = 1.0f / sqrtf(vs * (1.0f / DIMF) + 1e-5f);
        float4 g = *(const float4*)&g1[i4];
        float4 b = *(const float4*)&be1[i4];
        float4 base = *(const float4*)&cf[c4][i4];
        float4 r;
        r.x = base.x + d0 * rs * g.x + b.x;
        r.y = base.y + d1 * rs * g.y + b.y;
        r.z = base.z + d2 * rs * g.z + b.z;
        r.w = base.w + d3 * rs * g.w + b.w;
        *(float4*)&cf2[c4][i4] = r;
    }
    __syncthreads();

    // ---- H: FFN1 relu -> S1 ; 2 u-values/thread x 4 centers ----
    {
        int u0 = t & 127, pbase = t >> 7;  // p in {pbase, pbase+2}
        float acc[2][CB];
#pragma unroll
        for (int pp = 0; pp < 2; ++pp)
#pragma unroll
            for (int c = 0; c < CB; ++c) acc[pp][c] = 0.f;
        for (int jj = 0; jj < 32; ++jj) {
            float4 x[CB];
#pragma unroll
            for (int c = 0; c < CB; ++c) x[c] = *(const float4*)&cf2[c][jj * 4];
#pragma unroll
            for (int pp = 0; pp < 2; ++pp) {
                int u = (pbase + pp * 2) * DIMF + u0;
                float4 w = w1p4[jj * 512 + u];
#pragma unroll
                for (int c = 0; c < CB; ++c)
                    acc[pp][c] += w.x * x[c].x + w.y * x[c].y + w.z * x[c].z + w.w * x[c].w;
            }
        }
#pragma unroll
        for (int pp = 0; pp < 2; ++pp) {
            int u = (pbase + pp * 2) * DIMF + u0;
            float bb = b1f[u];
#pragma unroll
            for (int c = 0; c < CB; ++c) S1[c][u] = fmaxf(acc[pp][c] + bb, 0.f);
        }
    }
    __syncthreads();

    // ---- I: FFN2 -> S3 ; 2 centers/thread ----
    {
        int i = t & 127, cpair = (t >> 7) * 2;
        float acc0 = 0.f, acc1 = 0.f;
        for (int uu = 0; uu < 128; ++uu) {
            float4 w = w2p4[uu * DIMF + i];
            float4 h0v = *(const float4*)&S1[cpair][uu * 4];
            float4 h1v = *(const float4*)&S1[cpair + 1][uu * 4];
            acc0 += w.x * h0v.x + w.y * h0v.y + w.z * h0v.z + w.w * h0v.w;
            acc1 += w.x * h1v.x + w.y * h1v.y + w.z * h1v.z + w.w * h1v.w;
        }
        float bb = b2f[i];
        __syncthreads();
        S3[cpair][i] = acc0 + bb;
        S3[cpair + 1][i] = acc1 + bb;
    }
    __syncthreads();

    // ---- J: LN2 + residual -> cfin (128-thread map) ----
    if (t < 128) {
        int c4 = t >> 5, k32 = t & 31;
        int i4 = k32 * 4;
        float4 u = *(const float4*)&S3[c4][i4];
        float s = ((u.x + u.y) + u.z) + u.w;
        for (int o = 16; o; o >>= 1) s += __shfl_xor(s, o, 32);
        float mu = s * (1.0f / DIMF);
        float d0 = u.x - mu, d1 = u.y - mu, d2 = u.z - mu, d3 = u.w - mu;
        float vs = ((d0 * d0 + d1 * d1) + d2 * d2) + d3 * d3;
        for (int o = 16; o; o >>= 1) vs += __shfl_xor(vs, o, 32);
        float rs = 1.0f / sqrtf(vs * (1.0f / DIMF) + 1e-5f);
        float4 g = *(const float4*)&g2[i4];
        float4 b = *(const float4*)&be2[i4];
        float4 base = *(const float4*)&cf2[c4][i4];
        float4 r;
        r.x = base.x + d0 * rs * g.x + b.x;
        r.y = base.y + d1 * rs * g.y + b.y;
        r.z = base.z + d2 * rs * g.z + b.z;
        r.w = base.w + d3 * rs * g.w + b.w;
        *(float4*)&cfin[(long)(m0 + c4) * DIMF + i4] = r;
    }
}

// ================= kernel 3: out = feats + cfin[bestm] ======================
__global__ __launch_bounds__(256) void out_kernel(const float4* __restrict__ feats4,
                                                  const float* __restrict__ cfin,
                                                  const int* __restrict__ bestm,
                                                  float4* __restrict__ out4, int total) {
    int idx = blockIdx.x * 256 + threadIdx.x;
    if (idx >= total) return;
    int n = idx >> 5, c = idx & 31;
    const float4* cf4 = (const float4*)cfin;
    float4 f = feats4[idx];
    float4 g = cf4[(long)bestm[n] * 32 + c];
    out4[idx] = make_float4(f.x + g.x, f.y + g.y, f.z + g.z, f.w + g.w);
}

extern "C" void kernel_launch(void* const* d_in, const int* in_sizes, int n_in,
                              void* d_out, int out_size, void* d_ws, size_t ws_size,
                              hipStream_t stream) {
    const float* xyz = (const float*)d_in[0];
    const float* feats = (const float*)d_in[1];
    const int* idxc = (const int*)d_in[2];
    const float* Wq = (const float*)d_in[3];
    const float* Wk = (const float*)d_in[4];
    const float* Wv = (const float*)d_in[5];
    const float* Wo = (const float*)d_in[6];
    const float* bo = (const float*)d_in[7];
    const float* g1 = (const float*)d_in[8];
    const float* be1 = (const float*)d_in[9];
    const float* g2 = (const float*)d_in[10];
    const float* be2 = (const float*)d_in[11];
    const float* W1 = (const float*)d_in[12];
    const float* b1f = (const float*)d_in[13];
    const float* W2 = (const float*)d_in[14];
    const float* b2f = (const float*)d_in[15];

    int N = in_sizes[0] / 3;
    int M = in_sizes[2];

    char* ws = (char*)d_ws;
    size_t off = 0;
    float* cfin = (float*)(ws + off); off += (size_t)M * DIMF * 4;
    int* bestm = (int*)(ws + off); off += (size_t)N * 4;
    float4* qp4 = (float4*)(ws + off); off += (size_t)DIMF * DIMF * 4;
    float4* vp4 = (float4*)(ws + off); off += (size_t)DIMF * DIMF * 4;
    float4* op4 = (float4*)(ws + off); off += (size_t)DIMF * DIMF * 4;
    float4* kp4 = (float4*)(ws + off); off += (size_t)DIMF * DIMF * 4;
    float4* w1p4 = (float4*)(ws + off); off += (size_t)4 * DIMF * DIMF * 4;
    float4* w2p4 = (float4*)(ws + off); off += (size_t)4 * DIMF * DIMF * 4;
    (void)ws_size; (void)n_in; (void)out_size;

    pack_kernel<<<PACK_BLOCKS, 256, 0, stream>>>(
        Wq, Wv, Wo, W1, W2, Wk, qp4, vp4, op4, w1p4, w2p4, kp4);
    main_kernel<<<M / CB + N / PPB, TMAIN, 0, stream>>>(
        xyz, feats, idxc, qp4, kp4, vp4, op4, bo, g1, be1, g2, be2,
        w1p4, b1f, w2p4, b2f, cfin, bestm, N, M);
    out_kernel<<<(N * DIMF / 4 + 255) / 256, 256, 0, stream>>>(
        (const float4*)feats, cfin, bestm, (float4*)d_out, N * DIMF / 4);
}

// Round 5
// 190.164 us; speedup vs baseline: 1.0752x; 1.0752x over previous
//
#include <hip/hip_runtime.h>
#include <hip/hip_bf16.h>

#define DIMF 128
#define KNBR 32
#define NH 4
#define DH 32
#define RADIUS 0.3f
#define CB 8       // centers per attn block (R1 best-known structure)
#define CAND 256   // max candidates/center (Poisson max lambda~118)
#define PPB 32     // points per argmin block

#define PACK_BLOCKS 140    // 44 tr4 + 16 Wk-pack + 64 xyz4 + 16 cds4

typedef unsigned long long u64t;

// float4-granular transpose tile: out4[a*BI + b] = in4[b*AI + a]
__device__ __forceinline__ void tr4_tile(const float4* __restrict__ in4, float4* __restrict__ out4,
                                         int AI, int BI, int a0, int b0, int t, char* smem) {
    float4(*tile)[33] = (float4(*)[33])smem;
    int tx = t & 31, ty = t >> 5;  // 32 x 8
    for (int r = ty; r < 32; r += 8) tile[r][tx] = in4[(long)(b0 + r) * AI + a0 + tx];
    __syncthreads();
    for (int r = ty; r < 32; r += 8) out4[(long)(a0 + r) * BI + b0 + tx] = tile[tx][r];
}

// ====== kernel 1: weight packs + xyz4/cds4 precompute (true deps of main) ===
// xyz4 = (x,y,z,|p|^2): one coalesced f4 load replaces 3 strided loads + 3
// VALU in the scan AND argmin streams. cds4 = (-2cx,-2cy,-2cz,|c|^2): argmin
// staging becomes a coalesced copy (was idxc gather + 3 random xyz gathers +
// 4 VALU, x4096 per block x512 blocks). Same FMA expressions -> bit-identical.
__global__ __launch_bounds__(256) void pack_kernel(
    const float* __restrict__ xyz, const int* __restrict__ idxc,
    const float* __restrict__ Wq, const float* __restrict__ Wv,
    const float* __restrict__ Wo, const float* __restrict__ W1,
    const float* __restrict__ W2, const float* __restrict__ Wk,
    float4* __restrict__ qp4, float4* __restrict__ vp4, float4* __restrict__ op4,
    float4* __restrict__ w1p4, float4* __restrict__ w2p4, float4* __restrict__ kp4,
    float4* __restrict__ xyz4, float4* __restrict__ cds4, int N, int M) {
    __shared__ __align__(16) char smem[16896];
    int pk = blockIdx.x, t = threadIdx.x;
    if (pk < 4) {
        tr4_tile((const float4*)Wq, qp4, 32, 128, 0, pk * 32, t, smem);
    } else if (pk < 8) {
        tr4_tile((const float4*)Wv, vp4, 32, 128, 0, (pk - 4) * 32, t, smem);
    } else if (pk < 12) {
        tr4_tile((const float4*)Wo, op4, 32, 128, 0, (pk - 8) * 32, t, smem);
    } else if (pk < 28) {
        tr4_tile((const float4*)W1, w1p4, 32, 512, 0, (pk - 12) * 32, t, smem);
    } else if (pk < 44) {
        int i = pk - 28;
        tr4_tile((const float4*)W2, w2p4, 128, 128, (i >> 2) * 32, (i & 3) * 32, t, smem);
    } else if (pk < 60) {
        // Wk pack: kp4[q*128+j] = {Wk[(4q+r)*128+j]}_{r=0..3}
        int idx = (pk - 44) * 256 + t;
        int q = idx >> 7, j = idx & 127;
        float4 w;
        w.x = Wk[(long)(4 * q + 0) * DIMF + j];
        w.y = Wk[(long)(4 * q + 1) * DIMF + j];
        w.z = Wk[(long)(4 * q + 2) * DIMF + j];
        w.w = Wk[(long)(4 * q + 3) * DIMF + j];
        kp4[q * DIMF + j] = w;
    } else if (pk < 124) {
        int idx = (pk - 60) * 256 + t;
        if (idx < N) {
            float x = xyz[3 * idx], y = xyz[3 * idx + 1], z = xyz[3 * idx + 2];
            xyz4[idx] = make_float4(x, y, z, (x * x + y * y) + z * z);
        }
    } else {
        int idx = (pk - 124) * 256 + t;
        if (idx < M) {
            int ic = idxc[idx];
            float cx = xyz[3 * ic], cy = xyz[3 * ic + 1], cz = xyz[3 * ic + 2];
            cds4[idx] = make_float4(-2.0f * cx, -2.0f * cy, -2.0f * cz,
                                    (cx * cx + cy * cy) + cz * cz);
        }
    }
}

// ================= kernel 2: main — R1 structure + precomputed xyz4/cds4 ====
// R3/R4 post-mortem: both occupancy-targeted restructures regressed vs R1's
// CB=8/256t shape. Reverted to R1 verbatim; only the redundant per-block
// point/center transforms are hoisted into prep (xyz4/cds4).
__global__ __launch_bounds__(256) void main_kernel(
    const float4* __restrict__ xyz4, const float4* __restrict__ cds4g,
    const float* __restrict__ feats, const int* __restrict__ idxc,
    const float4* __restrict__ qp4, const float4* __restrict__ kp4,
    const float4* __restrict__ vp4, const float4* __restrict__ op4,
    const float* __restrict__ bo, const float* __restrict__ g1,
    const float* __restrict__ be1, const float* __restrict__ g2,
    const float* __restrict__ be2, const float4* __restrict__ w1p4,
    const float* __restrict__ b1f, const float4* __restrict__ w2p4,
    const float* __restrict__ b2f, float* __restrict__ cfin,
    int* __restrict__ bestm, int N, int M) {
    __shared__ __align__(16) char smem[32768];
    __shared__ int nbrl[CB][KNBR];
    __shared__ int cnt[CB];

    int t = threadIdx.x;
    int b = blockIdx.x;
    int nAttn = M / CB;

    if (b >= nAttn) {
        // ---------- nearest-center argmin, 32 pts/block, 8 lanes/pt ----------
        // Key: s = |c|^2 - 2 c.p (same argmin as d2; sqrt monotone). Exact-dup
        // centers give equal s -> lexicographic (s, index) min == np.argmin.
        float4* cds = (float4*)smem;
        int pt = t >> 3, q = t & 7;
        int n = (b - nAttn) * PPB + pt;
        float4 p4 = xyz4[n];
        float px = p4.x, py = p4.y, pz = p4.z;
        float bd0 = INFINITY, bd1 = INFINITY;
        int bm0 = 0, bm1 = 0;
        for (int c0 = 0; c0 < M; c0 += 1024) {
            __syncthreads();
            for (int i = t; i < 1024; i += 256) cds[i] = cds4g[c0 + i];
            __syncthreads();
#pragma unroll 8
            for (int i = 0; i < 64; ++i) {
                int ci0 = q + (2 * i) * 8, ci1 = q + (2 * i + 1) * 8;
                float4 ca = cds[ci0];
                float4 cb = cds[ci1];
                float sa = fmaf(ca.x, px, fmaf(ca.y, py, fmaf(ca.z, pz, ca.w)));
                float sb = fmaf(cb.x, px, fmaf(cb.y, py, fmaf(cb.z, pz, cb.w)));
                if (sa < bd0) { bd0 = sa; bm0 = c0 + ci0; }  // strict <: ascending scan keeps lowest idx
                if (sb < bd1) { bd1 = sb; bm1 = c0 + ci1; }
            }
        }
        if (bd1 < bd0 || (bd1 == bd0 && bm1 < bm0)) { bd0 = bd1; bm0 = bm1; }
#pragma unroll
        for (int o = 1; o < 8; o <<= 1) {
            float obd = __shfl_xor(bd0, o);
            int obm = __shfl_xor(bm0, o);
            if (obd < bd0 || (obd == bd0 && obm < bm0)) { bd0 = obd; bm0 = obm; }
        }
        if (q == 0) bestm[n] = bm0;
        return;
    }

    int m0 = b * CB;

    // ======== phase 1: radius top-K for centers m0..m0+7 ========
    {
        u64t(*cand)[CAND] = (u64t(*)[CAND])smem;
        if (t < CB) cnt[t] = 0;
        __syncthreads();
        float nx[CB], ny[CB], nz[CB], cw[CB];
#pragma unroll
        for (int tc = 0; tc < CB; ++tc) {
            float4 c4v = cds4g[m0 + tc];
            nx[tc] = c4v.x; ny[tc] = c4v.y; nz[tc] = c4v.z; cw[tc] = c4v.w;
        }
        const float R2 = RADIUS * RADIUS;
        for (int n = t; n < N; n += 256) {
            float4 p4 = xyz4[n];
            float rhs = R2 - p4.w;  // s < rhs  <=>  s + pw < R2
#pragma unroll
            for (int tc = 0; tc < CB; ++tc) {
                float s = fmaf(nx[tc], p4.x, fmaf(ny[tc], p4.y, fmaf(nz[tc], p4.z, cw[tc])));
                if (s < rhs) {
                    int pos = atomicAdd(&cnt[tc], 1);
                    if (pos < CAND)
                        cand[tc][pos] = (((u64t)__float_as_uint(fmaxf(s + p4.w, 0.0f))) << 32) | (unsigned)n;
                }
            }
        }
        __syncthreads();
        // wave w extracts centers w and w+4 via rank-select into LDS nbrl
        int w = t >> 6, lane = t & 63;
        for (int rep = 0; rep < 2; ++rep) {
            int cidx = w + rep * 4;
            int C = cnt[cidx] < CAND ? cnt[cidx] : CAND;
            const u64t* vc = cand[cidx];
            if (C <= 64) {
                u64t mykey = (lane < C) ? vc[lane] : ~0ull;
                int rank = 0;
                for (int j = 0; j < C; ++j) rank += (vc[j] < mykey) ? 1 : 0;
                if (lane < C && rank < KNBR) nbrl[cidx][rank] = (int)(mykey & 0xffffffffu);
                if (lane >= C && lane < KNBR) nbrl[cidx][lane] = -1;
            } else {
                u64t mykey[4];
                int myrank[4];
#pragma unroll
                for (int s = 0; s < 4; ++s) {
                    int i = s * 64 + lane;
                    mykey[s] = (i < C) ? vc[i] : ~0ull;
                    myrank[s] = 0;
                }
                for (int j = 0; j < C; ++j) {
                    u64t kj = vc[j];
#pragma unroll
                    for (int s = 0; s < 4; ++s) myrank[s] += (kj < mykey[s]) ? 1 : 0;
                }
#pragma unroll
                for (int s = 0; s < 4; ++s) {
                    int i = s * 64 + lane;
                    if (i < C && myrank[s] < KNBR) nbrl[cidx][myrank[s]] = (int)(mykey[s] & 0xffffffffu);
                }
            }
        }
    }
    __syncthreads();  // cand reads done; smem becomes attn buffers

    // ======== phase 2: attention + FFN (R1 structure) ========
    float(*cf)[DIMF] = (float(*)[DIMF])smem;
    float(*cf2)[DIMF] = (float(*)[DIMF])(smem + 4096);
    float(*S1)[4 * DIMF] = (float(*)[4 * DIMF])(smem + 8192);
    float(*S2)[DIMF] = (float(*)[DIMF])(smem + 24576);
    float(*S3)[DIMF] = (float(*)[DIMF])(smem + 28672);

    int lane127 = t & 127;
    int cg = (t >> 7) * 4;
    int c8 = t >> 5, k32 = t & 31;

    {
        int ic = idxc[m0 + c8];
        *(float4*)&cf[c8][k32 * 4] = *(const float4*)&feats[(long)ic * DIMF + k32 * 4];
    }
    __syncthreads();

    // ---- A: q = Wq @ cf (scaled) -> S2 ----
    {
        float acc[4] = {0.f, 0.f, 0.f, 0.f};
        for (int jj = 0; jj < 32; ++jj) {
            float4 w = qp4[jj * DIMF + lane127];
#pragma unroll
            for (int cc = 0; cc < 4; ++cc) {
                float4 x = *(const float4*)&cf[cg + cc][jj * 4];
                acc[cc] += w.x * x.x + w.y * x.y + w.z * x.z + w.w * x.w;
            }
        }
#pragma unroll
        for (int cc = 0; cc < 4; ++cc) S2[cg + cc][lane127] = acc[cc] * 0.17677669529663687f;
    }
    __syncthreads();

    // ---- B: qw[c][h][j] -> S1 ----
    {
        int j = lane127, hs = t >> 7;
#pragma unroll
        for (int hh = 0; hh < 2; ++hh) {
            int h = hs * 2 + hh;
            float acc[8] = {0.f, 0.f, 0.f, 0.f, 0.f, 0.f, 0.f, 0.f};
            for (int d4 = 0; d4 < 8; ++d4) {
                float4 w = kp4[(h * 8 + d4) * DIMF + j];
#pragma unroll
                for (int c = 0; c < 8; ++c) {
                    float4 qv = *(const float4*)&S2[c][h * DH + d4 * 4];
                    acc[c] += qv.x * w.x + qv.y * w.y + qv.z * w.z + qv.w * w.w;
                }
            }
#pragma unroll
            for (int c = 0; c < 8; ++c) S1[c][h * DIMF + j] = acc[c];
        }
    }
    __syncthreads();

    // ---- C: logits + softmax -> S3 ----
    {
        int ni = nbrl[c8][k32];
        const float* nrow = feats + (long)(ni < 0 ? 0 : ni) * DIMF;
        float lg[4] = {0.f, 0.f, 0.f, 0.f};
        for (int jj = 0; jj < 32; ++jj) {
            float4 f = *(const float4*)&nrow[jj * 4];
#pragma unroll
            for (int h = 0; h < 4; ++h) {
                float4 qwv = *(const float4*)&S1[c8][h * DIMF + jj * 4];
                lg[h] += f.x * qwv.x + f.y * qwv.y + f.z * qwv.z + f.w * qwv.w;
            }
        }
        if (ni < 0) { lg[0] = -1e9f; lg[1] = -1e9f; lg[2] = -1e9f; lg[3] = -1e9f; }
#pragma unroll
        for (int h = 0; h < 4; ++h) {
            float mx = lg[h];
            for (int o = 16; o; o >>= 1) mx = fmaxf(mx, __shfl_xor(mx, o, 32));
            float e = expf(lg[h] - mx);
            float s = e;
            for (int o = 16; o; o >>= 1) s += __shfl_xor(s, o, 32);
            S3[c8][h * KNBR + k32] = e / s;
        }
    }
    __syncthreads();

    // ---- D: pool -> S1 (overwrite qw) ----
    {
        int j4 = k32 * 4;
        float a0x = 0.f, a0y = 0.f, a0z = 0.f, a0w = 0.f;
        float a1x = 0.f, a1y = 0.f, a1z = 0.f, a1w = 0.f;
        float a2x = 0.f, a2y = 0.f, a2z = 0.f, a2w = 0.f;
        float a3x = 0.f, a3y = 0.f, a3z = 0.f, a3w = 0.f;
        for (int k = 0; k < KNBR; ++k) {
            int ni = nbrl[c8][k];
            const float* nrow = feats + (long)(ni < 0 ? 0 : ni) * DIMF;
            float4 f = *(const float4*)&nrow[j4];
            float w0 = S3[c8][0 * KNBR + k], w1 = S3[c8][1 * KNBR + k];
            float w2 = S3[c8][2 * KNBR + k], w3 = S3[c8][3 * KNBR + k];
            a0x += w0 * f.x; a0y += w0 * f.y; a0z += w0 * f.z; a0w += w0 * f.w;
            a1x += w1 * f.x; a1y += w1 * f.y; a1z += w1 * f.z; a1w += w1 * f.w;
            a2x += w2 * f.x; a2y += w2 * f.y; a2z += w2 * f.z; a2w += w2 * f.w;
            a3x += w3 * f.x; a3y += w3 * f.y; a3z += w3 * f.z; a3w += w3 * f.w;
        }
        __syncthreads();
        *(float4*)&S1[c8][0 * DIMF + j4] = make_float4(a0x, a0y, a0z, a0w);
        *(float4*)&S1[c8][1 * DIMF + j4] = make_float4(a1x, a1y, a1z, a1w);
        *(float4*)&S1[c8][2 * DIMF + j4] = make_float4(a2x, a2y, a2z, a2w);
        *(float4*)&S1[c8][3 * DIMF + j4] = make_float4(a3x, a3y, a3z, a3w);
    }
    __syncthreads();

    // ---- E: updin -> S2 ----
    {
        int i = lane127, h = i >> 5, d = i & 31;
        float acc[4] = {0.f, 0.f, 0.f, 0.f};
        for (int jj = 0; jj < 32; ++jj) {
            float4 w = vp4[jj * DIMF + i];
#pragma unroll
            for (int cc = 0; cc < 4; ++cc) {
                float4 pv = *(const float4*)&S1[cg + cc][h * DIMF + jj * 4];
                acc[cc] += w.x * pv.x + w.y * pv.y + w.z * pv.z + w.w * pv.w;
            }
        }
        __syncthreads();
#pragma unroll
        for (int cc = 0; cc < 4; ++cc) S2[cg + cc][d * NH + h] = acc[cc];
    }
    __syncthreads();

    // ---- F: upd = Wo @ updin + bo -> S3 ----
    {
        int i = lane127;
        float acc[4] = {0.f, 0.f, 0.f, 0.f};
        for (int jj = 0; jj < 32; ++jj) {
            float4 w = op4[jj * DIMF + i];
#pragma unroll
            for (int cc = 0; cc < 4; ++cc) {
                float4 x = *(const float4*)&S2[cg + cc][jj * 4];
                acc[cc] += w.x * x.x + w.y * x.y + w.z * x.z + w.w * x.w;
            }
        }
        float b = bo[i];
        __syncthreads();
#pragma unroll
        for (int cc = 0; cc < 4; ++cc) S3[cg + cc][i] = acc[cc] + b;
    }
    __syncthreads();

    // ---- G: LN1 + residual -> cf2 ----
    {
        int i4 = k32 * 4;
        float4 u = *(const float4*)&S3[c8][i4];
        float s = ((u.x + u.y) + u.z) + u.w;
        for (int o = 16; o; o >>= 1) s += __shfl_xor(s, o, 32);
        float mu = s * (1.0f / DIMF);
        float d0 = u.x - mu, d1 = u.y - mu, d2 = u.z - mu, d3 = u.w - mu;
        float vs = ((d0 * d0 + d1 * d1) + d2 * d2) + d3 * d3;
        for (int o = 16; o; o >>= 1) vs += __shfl_xor(vs, o, 32);
        float rs = 1.0f / sqrtf(vs * (1.0f / DIMF) + 1e-5f);
        float4 g = *(const float4*)&g1[i4];
        float4 b = *(const float4*)&be1[i4];
        float4 base = *(const float4*)&cf[c8][i4];
        float4 r;
        r.x = base.x + d0 * rs * g.x + b.x;
        r.y = base.y + d1 * rs * g.y + b.y;
        r.z = base.z + d2 * rs * g.z + b.z;
        r.w = base.w + d3 * rs * g.w + b.w;
        *(float4*)&cf2[c8][i4] = r;
    }
    __syncthreads();

    // ---- H: FFN1 relu -> S1 ----
    {
        int u0 = lane127;
        float acc[4][4];
#pragma unroll
        for (int p = 0; p < 4; ++p)
#pragma unroll
            for (int cc = 0; cc < 4; ++cc) acc[p][cc] = 0.f;
        for (int jj = 0; jj < 32; ++jj) {
            float4 x[4];
#pragma unroll
            for (int cc = 0; cc < 4; ++cc) x[cc] = *(const float4*)&cf2[cg + cc][jj * 4];
#pragma unroll
            for (int p = 0; p < 4; ++p) {
                float4 w = w1p4[jj * 512 + u0 + p * DIMF];
#pragma unroll
                for (int cc = 0; cc < 4; ++cc)
                    acc[p][cc] += w.x * x[cc].x + w.y * x[cc].y + w.z * x[cc].z + w.w * x[cc].w;
            }
        }
#pragma unroll
        for (int p = 0; p < 4; ++p) {
            float b = b1f[u0 + p * DIMF];
#pragma unroll
            for (int cc = 0; cc < 4; ++cc)
                S1[cg + cc][u0 + p * DIMF] = fmaxf(acc[p][cc] + b, 0.f);
        }
    }
    __syncthreads();

    // ---- I: FFN2 -> S3 ----
    {
        int i = lane127;
        float acc[4] = {0.f, 0.f, 0.f, 0.f};
        for (int uu = 0; uu < 128; ++uu) {
            float4 w = w2p4[uu * DIMF + i];
#pragma unroll
            for (int cc = 0; cc < 4; ++cc) {
                float4 hh = *(const float4*)&S1[cg + cc][uu * 4];
                acc[cc] += w.x * hh.x + w.y * hh.y + w.z * hh.z + w.w * hh.w;
            }
        }
        float b = b2f[i];
        __syncthreads();
#pragma unroll
        for (int cc = 0; cc < 4; ++cc) S3[cg + cc][i] = acc[cc] + b;
    }
    __syncthreads();

    // ---- J: LN2 + residual -> cfin ----
    {
        int i4 = k32 * 4;
        float4 u = *(const float4*)&S3[c8][i4];
        float s = ((u.x + u.y) + u.z) + u.w;
        for (int o = 16; o; o >>= 1) s += __shfl_xor(s, o, 32);
        float mu = s * (1.0f / DIMF);
        float d0 = u.x - mu, d1 = u.y - mu, d2 = u.z - mu, d3 = u.w - mu;
        float vs = ((d0 * d0 + d1 * d1) + d2 * d2) + d3 * d3;
        for (int o = 16; o; o >>= 1) vs += __shfl_xor(vs, o, 32);
        float rs = 1.0f / sqrtf(vs * (1.0f / DIMF) + 1e-5f);
        float4 g = *(const float4*)&g2[i4];
        float4 b = *(const float4*)&be2[i4];
        float4 base = *(const float4*)&cf2[c8][i4];
        float4 r;
        r.x = base.x + d0 * rs * g.x + b.x;
        r.y = base.y + d1 * rs * g.y + b.y;
        r.z = base.z + d2 * rs * g.z + b.z;
        r.w = base.w + d3 * rs * g.w + b.w;
        *(float4*)&cfin[(long)(m0 + c8) * DIMF + i4] = r;
    }
}

// ================= kernel 3: out = feats + cfin[bestm] ======================
__global__ __launch_bounds__(256) void out_kernel(const float4* __restrict__ feats4,
                                                  const float* __restrict__ cfin,
                                                  const int* __restrict__ bestm,
                                                  float4* __restrict__ out4, int total) {
    int idx = blockIdx.x * 256 + threadIdx.x;
    if (idx >= total) return;
    int n = idx >> 5, c = idx & 31;
    const float4* cf4 = (const float4*)cfin;
    float4 f = feats4[idx];
    float4 g = cf4[(long)bestm[n] * 32 + c];
    out4[idx] = make_float4(f.x + g.x, f.y + g.y, f.z + g.z, f.w + g.w);
}

extern "C" void kernel_launch(void* const* d_in, const int* in_sizes, int n_in,
                              void* d_out, int out_size, void* d_ws, size_t ws_size,
                              hipStream_t stream) {
    const float* xyz = (const float*)d_in[0];
    const float* feats = (const float*)d_in[1];
    const int* idxc = (const int*)d_in[2];
    const float* Wq = (const float*)d_in[3];
    const float* Wk = (const float*)d_in[4];
    const float* Wv = (const float*)d_in[5];
    const float* Wo = (const float*)d_in[6];
    const float* bo = (const float*)d_in[7];
    const float* g1 = (const float*)d_in[8];
    const float* be1 = (const float*)d_in[9];
    const float* g2 = (const float*)d_in[10];
    const float* be2 = (const float*)d_in[11];
    const float* W1 = (const float*)d_in[12];
    const float* b1f = (const float*)d_in[13];
    const float* W2 = (const float*)d_in[14];
    const float* b2f = (const float*)d_in[15];

    int N = in_sizes[0] / 3;
    int M = in_sizes[2];

    char* ws = (char*)d_ws;
    size_t off = 0;
    float* cfin = (float*)(ws + off); off += (size_t)M * DIMF * 4;
    int* bestm = (int*)(ws + off); off += (size_t)N * 4;
    float4* qp4 = (float4*)(ws + off); off += (size_t)DIMF * DIMF * 4;
    float4* vp4 = (float4*)(ws + off); off += (size_t)DIMF * DIMF * 4;
    float4* op4 = (float4*)(ws + off); off += (size_t)DIMF * DIMF * 4;
    float4* kp4 = (float4*)(ws + off); off += (size_t)DIMF * DIMF * 4;
    float4* w1p4 = (float4*)(ws + off); off += (size_t)4 * DIMF * DIMF * 4;
    float4* w2p4 = (float4*)(ws + off); off += (size_t)4 * DIMF * DIMF * 4;
    float4* xyz4 = (float4*)(ws + off); off += (size_t)N * 16;
    float4* cds4 = (float4*)(ws + off); off += (size_t)M * 16;
    (void)ws_size; (void)n_in; (void)out_size;

    pack_kernel<<<PACK_BLOCKS, 256, 0, stream>>>(
        xyz, idxc, Wq, Wv, Wo, W1, W2, Wk,
        qp4, vp4, op4, w1p4, w2p4, kp4, xyz4, cds4, N, M);
    main_kernel<<<M / CB + N / PPB, 256, 0, stream>>>(
        xyz4, cds4, feats, idxc, qp4, kp4, vp4, op4, bo, g1, be1, g2, be2,
        w1p4, b1f, w2p4, b2f, cfin, bestm, N, M);
    out_kernel<<<(N * DIMF / 4 + 255) / 256, 256, 0, stream>>>(
        (const float4*)feats, cfin, bestm, (float4*)d_out, N * DIMF / 4);
}

// Round 6
// 167.932 us; speedup vs baseline: 1.2175x; 1.1324x over previous
//
#include <hip/hip_runtime.h>
#include <hip/hip_bf16.h>

#define DIMF 128
#define KNBR 32
#define NH 4
#define DH 32
#define RADIUS 0.3f
#define CB 8       // centers per attn block (R1 best-known structure)
#define CAND 256   // max candidates/center (Poisson max lambda~118)
#define PPB 32     // points per argmin block

#define PACK_BLOCKS 172    // 12 tr4 + 16 Wk + 64 xyz4 + 16 cds4 + 32 w1h + 32 w2h

typedef unsigned long long u64t;
typedef _Float16 f16x8 __attribute__((ext_vector_type(8)));
typedef _Float16 f16x4 __attribute__((ext_vector_type(4)));
typedef float f32x4 __attribute__((ext_vector_type(4)));

// float4-granular transpose tile: out4[a*BI + b] = in4[b*AI + a]
__device__ __forceinline__ void tr4_tile(const float4* __restrict__ in4, float4* __restrict__ out4,
                                         int AI, int BI, int a0, int b0, int t, char* smem) {
    float4(*tile)[33] = (float4(*)[33])smem;
    int tx = t & 31, ty = t >> 5;  // 32 x 8
    for (int r = ty; r < 32; r += 8) tile[r][tx] = in4[(long)(b0 + r) * AI + a0 + tx];
    __syncthreads();
    for (int r = ty; r < 32; r += 8) out4[(long)(a0 + r) * BI + b0 + tx] = tile[tx][r];
}

// ====== kernel 1: weight packs + xyz4/cds4 + f16 MFMA weight packs ==========
// w1h/w2h: B-operand fragments for mfma_f32_16x16x32_f16, pre-converted to f16
// and laid out so lane l of tile (nt,ks) loads its 8 elements with ONE
// coalesced 16B global load (VMEM pipe — keeps the FFN GEMMs off the LDS pipe).
// B[k][n] frag layout: lane l holds col n = nt*16+(l&15), k = ks*32+(l>>4)*8+j.
__global__ __launch_bounds__(256) void pack_kernel(
    const float* __restrict__ xyz, const int* __restrict__ idxc,
    const float* __restrict__ Wq, const float* __restrict__ Wv,
    const float* __restrict__ Wo, const float* __restrict__ W1,
    const float* __restrict__ W2, const float* __restrict__ Wk,
    float4* __restrict__ qp4, float4* __restrict__ vp4, float4* __restrict__ op4,
    float4* __restrict__ kp4, f16x8* __restrict__ w1h, f16x8* __restrict__ w2h,
    float4* __restrict__ xyz4, float4* __restrict__ cds4, int N, int M) {
    __shared__ __align__(16) char smem[16896];
    int pk = blockIdx.x, t = threadIdx.x;
    if (pk < 4) {
        tr4_tile((const float4*)Wq, qp4, 32, 128, 0, pk * 32, t, smem);
    } else if (pk < 8) {
        tr4_tile((const float4*)Wv, vp4, 32, 128, 0, (pk - 4) * 32, t, smem);
    } else if (pk < 12) {
        tr4_tile((const float4*)Wo, op4, 32, 128, 0, (pk - 8) * 32, t, smem);
    } else if (pk < 28) {
        // Wk pack: kp4[q*128+j] = {Wk[(4q+r)*128+j]}_{r=0..3}
        int idx = (pk - 12) * 256 + t;
        int q = idx >> 7, j = idx & 127;
        float4 w;
        w.x = Wk[(long)(4 * q + 0) * DIMF + j];
        w.y = Wk[(long)(4 * q + 1) * DIMF + j];
        w.z = Wk[(long)(4 * q + 2) * DIMF + j];
        w.w = Wk[(long)(4 * q + 3) * DIMF + j];
        kp4[q * DIMF + j] = w;
    } else if (pk < 92) {
        int idx = (pk - 28) * 256 + t;
        if (idx < N) {
            float x = xyz[3 * idx], y = xyz[3 * idx + 1], z = xyz[3 * idx + 2];
            xyz4[idx] = make_float4(x, y, z, (x * x + y * y) + z * z);
        }
    } else if (pk < 108) {
        int idx = (pk - 92) * 256 + t;
        if (idx < M) {
            int ic = idxc[idx];
            float cx = xyz[3 * ic], cy = xyz[3 * ic + 1], cz = xyz[3 * ic + 2];
            cds4[idx] = make_float4(-2.0f * cx, -2.0f * cy, -2.0f * cz,
                                    (cx * cx + cy * cy) + cz * cz);
        }
    } else if (pk < 140) {
        // w1h: B-frags of W1^T [128 x 512]; nt(32) x ks(4) x lane(64)
        int e = (pk - 108) * 256 + t;
        int l = e & 63, ks = (e >> 6) & 3, nt = e >> 8;
        int row = nt * 16 + (l & 15);          // n (W1 row)
        int cb = ks * 32 + (l >> 4) * 8;       // k (W1 col)
        const float* src = W1 + (long)row * DIMF + cb;
        f16x8 v;
#pragma unroll
        for (int j = 0; j < 8; ++j) v[j] = (_Float16)src[j];
        w1h[e] = v;
    } else {
        // w2h: B-frags of W2^T [512 x 128]; nt(8) x ks(16) x lane(64)
        int e = (pk - 140) * 256 + t;
        int l = e & 63, ks = (e >> 6) & 15, nt = e >> 10;
        int row = nt * 16 + (l & 15);          // n (W2 row)
        int cb = ks * 32 + (l >> 4) * 8;       // k (W2 col)
        const float* src = W2 + (long)row * (4 * DIMF) + cb;
        f16x8 v;
#pragma unroll
        for (int j = 0; j < 8; ++j) v[j] = (_Float16)src[j];
        w2h[e] = v;
    }
}

// ================= kernel 2: main ===========================================
// R5 post-mortem: kernel is LDS-READ-THROUGHPUT bound (ds_read_b128 ~12cyc;
// ~1280 reads/thread x 4 waves x 4 blocks/CU x 12cyc ~= the whole 105us).
// H+I (FFN) were 640 of those 1280 reads -> moved to f16 MFMA: A-frags from
// LDS (8-32 reads/wave, XOR-swizzled), B-frags straight from global (VMEM
// pipe), accumulate in f32. M padded 8->16; discarded rows are independent.
__global__ __launch_bounds__(256) void main_kernel(
    const float4* __restrict__ xyz4, const float4* __restrict__ cds4g,
    const float* __restrict__ feats, const int* __restrict__ idxc,
    const float4* __restrict__ qp4, const float4* __restrict__ kp4,
    const float4* __restrict__ vp4, const float4* __restrict__ op4,
    const float* __restrict__ bo, const float* __restrict__ g1,
    const float* __restrict__ be1, const float* __restrict__ g2,
    const float* __restrict__ be2, const f16x8* __restrict__ w1h,
    const float* __restrict__ b1f, const f16x8* __restrict__ w2h,
    const float* __restrict__ b2f, float* __restrict__ cfin,
    int* __restrict__ bestm, int N, int M) {
    __shared__ __align__(16) char smem[32768];
    __shared__ int nbrl[CB][KNBR];
    __shared__ int cnt[CB];

    int t = threadIdx.x;
    int b = blockIdx.x;
    int nAttn = M / CB;

    if (b >= nAttn) {
        // ---------- nearest-center argmin, 32 pts/block, 8 lanes/pt ----------
        float4* cds = (float4*)smem;
        int pt = t >> 3, q = t & 7;
        int n = (b - nAttn) * PPB + pt;
        float4 p4 = xyz4[n];
        float px = p4.x, py = p4.y, pz = p4.z;
        float bd0 = INFINITY, bd1 = INFINITY;
        int bm0 = 0, bm1 = 0;
        for (int c0 = 0; c0 < M; c0 += 1024) {
            __syncthreads();
            for (int i = t; i < 1024; i += 256) cds[i] = cds4g[c0 + i];
            __syncthreads();
#pragma unroll 8
            for (int i = 0; i < 64; ++i) {
                int ci0 = q + (2 * i) * 8, ci1 = q + (2 * i + 1) * 8;
                float4 ca = cds[ci0];
                float4 cb = cds[ci1];
                float sa = fmaf(ca.x, px, fmaf(ca.y, py, fmaf(ca.z, pz, ca.w)));
                float sb = fmaf(cb.x, px, fmaf(cb.y, py, fmaf(cb.z, pz, cb.w)));
                if (sa < bd0) { bd0 = sa; bm0 = c0 + ci0; }
                if (sb < bd1) { bd1 = sb; bm1 = c0 + ci1; }
            }
        }
        if (bd1 < bd0 || (bd1 == bd0 && bm1 < bm0)) { bd0 = bd1; bm0 = bm1; }
#pragma unroll
        for (int o = 1; o < 8; o <<= 1) {
            float obd = __shfl_xor(bd0, o);
            int obm = __shfl_xor(bm0, o);
            if (obd < bd0 || (obd == bd0 && obm < bm0)) { bd0 = obd; bm0 = obm; }
        }
        if (q == 0) bestm[n] = bm0;
        return;
    }

    int m0 = b * CB;

    // ======== phase 1: radius top-K for centers m0..m0+7 ========
    {
        u64t(*cand)[CAND] = (u64t(*)[CAND])smem;
        if (t < CB) cnt[t] = 0;
        __syncthreads();
        float nx[CB], ny[CB], nz[CB], cw[CB];
#pragma unroll
        for (int tc = 0; tc < CB; ++tc) {
            float4 c4v = cds4g[m0 + tc];
            nx[tc] = c4v.x; ny[tc] = c4v.y; nz[tc] = c4v.z; cw[tc] = c4v.w;
        }
        const float R2 = RADIUS * RADIUS;
        for (int n = t; n < N; n += 256) {
            float4 p4 = xyz4[n];
            float rhs = R2 - p4.w;
#pragma unroll
            for (int tc = 0; tc < CB; ++tc) {
                float s = fmaf(nx[tc], p4.x, fmaf(ny[tc], p4.y, fmaf(nz[tc], p4.z, cw[tc])));
                if (s < rhs) {
                    int pos = atomicAdd(&cnt[tc], 1);
                    if (pos < CAND)
                        cand[tc][pos] = (((u64t)__float_as_uint(fmaxf(s + p4.w, 0.0f))) << 32) | (unsigned)n;
                }
            }
        }
        __syncthreads();
        int w = t >> 6, lane = t & 63;
        for (int rep = 0; rep < 2; ++rep) {
            int cidx = w + rep * 4;
            int C = cnt[cidx] < CAND ? cnt[cidx] : CAND;
            const u64t* vc = cand[cidx];
            if (C <= 64) {
                u64t mykey = (lane < C) ? vc[lane] : ~0ull;
                int rank = 0;
                for (int j = 0; j < C; ++j) rank += (vc[j] < mykey) ? 1 : 0;
                if (lane < C && rank < KNBR) nbrl[cidx][rank] = (int)(mykey & 0xffffffffu);
                if (lane >= C && lane < KNBR) nbrl[cidx][lane] = -1;
            } else {
                u64t mykey[4];
                int myrank[4];
#pragma unroll
                for (int s = 0; s < 4; ++s) {
                    int i = s * 64 + lane;
                    mykey[s] = (i < C) ? vc[i] : ~0ull;
                    myrank[s] = 0;
                }
                for (int j = 0; j < C; ++j) {
                    u64t kj = vc[j];
#pragma unroll
                    for (int s = 0; s < 4; ++s) myrank[s] += (kj < mykey[s]) ? 1 : 0;
                }
#pragma unroll
                for (int s = 0; s < 4; ++s) {
                    int i = s * 64 + lane;
                    if (i < C && myrank[s] < KNBR) nbrl[cidx][myrank[s]] = (int)(mykey[s] & 0xffffffffu);
                }
            }
        }
    }
    __syncthreads();  // cand reads done; smem becomes attn buffers

    // ======== phase 2: attention + FFN ========
    // LDS map: cf@0(4K), cf2@4096(4K), S1@8192(16K: qw -> pool -> hid f16),
    // S2@24576(4K: q -> updin -> cf2h f16), S3@28672(4K: softmax -> upd -> FFN out)
    float(*cf)[DIMF] = (float(*)[DIMF])smem;
    float(*cf2)[DIMF] = (float(*)[DIMF])(smem + 4096);
    float(*S1)[4 * DIMF] = (float(*)[4 * DIMF])(smem + 8192);
    float(*S2)[DIMF] = (float(*)[DIMF])(smem + 24576);
    float(*S3)[DIMF] = (float(*)[DIMF])(smem + 28672);

    int lane127 = t & 127;
    int cg = (t >> 7) * 4;
    int c8 = t >> 5, k32 = t & 31;

    {
        int ic = idxc[m0 + c8];
        *(float4*)&cf[c8][k32 * 4] = *(const float4*)&feats[(long)ic * DIMF + k32 * 4];
    }
    __syncthreads();

    // ---- A: q = Wq @ cf (scaled) -> S2 ----
    {
        float acc[4] = {0.f, 0.f, 0.f, 0.f};
        for (int jj = 0; jj < 32; ++jj) {
            float4 w = qp4[jj * DIMF + lane127];
#pragma unroll
            for (int cc = 0; cc < 4; ++cc) {
                float4 x = *(const float4*)&cf[cg + cc][jj * 4];
                acc[cc] += w.x * x.x + w.y * x.y + w.z * x.z + w.w * x.w;
            }
        }
#pragma unroll
        for (int cc = 0; cc < 4; ++cc) S2[cg + cc][lane127] = acc[cc] * 0.17677669529663687f;
    }
    __syncthreads();

    // ---- B: qw[c][h][j] -> S1 ----
    {
        int j = lane127, hs = t >> 7;
#pragma unroll
        for (int hh = 0; hh < 2; ++hh) {
            int h = hs * 2 + hh;
            float acc[8] = {0.f, 0.f, 0.f, 0.f, 0.f, 0.f, 0.f, 0.f};
            for (int d4 = 0; d4 < 8; ++d4) {
                float4 w = kp4[(h * 8 + d4) * DIMF + j];
#pragma unroll
                for (int c = 0; c < 8; ++c) {
                    float4 qv = *(const float4*)&S2[c][h * DH + d4 * 4];
                    acc[c] += qv.x * w.x + qv.y * w.y + qv.z * w.z + qv.w * w.w;
                }
            }
#pragma unroll
            for (int c = 0; c < 8; ++c) S1[c][h * DIMF + j] = acc[c];
        }
    }
    __syncthreads();

    // ---- C: logits + softmax -> S3 ----
    {
        int ni = nbrl[c8][k32];
        const float* nrow = feats + (long)(ni < 0 ? 0 : ni) * DIMF;
        float lg[4] = {0.f, 0.f, 0.f, 0.f};
        for (int jj = 0; jj < 32; ++jj) {
            float4 f = *(const float4*)&nrow[jj * 4];
#pragma unroll
            for (int h = 0; h < 4; ++h) {
                float4 qwv = *(const float4*)&S1[c8][h * DIMF + jj * 4];
                lg[h] += f.x * qwv.x + f.y * qwv.y + f.z * qwv.z + f.w * qwv.w;
            }
        }
        if (ni < 0) { lg[0] = -1e9f; lg[1] = -1e9f; lg[2] = -1e9f; lg[3] = -1e9f; }
#pragma unroll
        for (int h = 0; h < 4; ++h) {
            float mx = lg[h];
            for (int o = 16; o; o >>= 1) mx = fmaxf(mx, __shfl_xor(mx, o, 32));
            float e = expf(lg[h] - mx);
            float s = e;
            for (int o = 16; o; o >>= 1) s += __shfl_xor(s, o, 32);
            S3[c8][h * KNBR + k32] = e / s;
        }
    }
    __syncthreads();

    // ---- D: pool -> S1 (overwrite qw) ----
    {
        int j4 = k32 * 4;
        float a0x = 0.f, a0y = 0.f, a0z = 0.f, a0w = 0.f;
        float a1x = 0.f, a1y = 0.f, a1z = 0.f, a1w = 0.f;
        float a2x = 0.f, a2y = 0.f, a2z = 0.f, a2w = 0.f;
        float a3x = 0.f, a3y = 0.f, a3z = 0.f, a3w = 0.f;
        for (int k = 0; k < KNBR; ++k) {
            int ni = nbrl[c8][k];
            const float* nrow = feats + (long)(ni < 0 ? 0 : ni) * DIMF;
            float4 f = *(const float4*)&nrow[j4];
            float w0 = S3[c8][0 * KNBR + k], w1 = S3[c8][1 * KNBR + k];
            float w2 = S3[c8][2 * KNBR + k], w3 = S3[c8][3 * KNBR + k];
            a0x += w0 * f.x; a0y += w0 * f.y; a0z += w0 * f.z; a0w += w0 * f.w;
            a1x += w1 * f.x; a1y += w1 * f.y; a1z += w1 * f.z; a1w += w1 * f.w;
            a2x += w2 * f.x; a2y += w2 * f.y; a2z += w2 * f.z; a2w += w2 * f.w;
            a3x += w3 * f.x; a3y += w3 * f.y; a3z += w3 * f.z; a3w += w3 * f.w;
        }
        __syncthreads();
        *(float4*)&S1[c8][0 * DIMF + j4] = make_float4(a0x, a0y, a0z, a0w);
        *(float4*)&S1[c8][1 * DIMF + j4] = make_float4(a1x, a1y, a1z, a1w);
        *(float4*)&S1[c8][2 * DIMF + j4] = make_float4(a2x, a2y, a2z, a2w);
        *(float4*)&S1[c8][3 * DIMF + j4] = make_float4(a3x, a3y, a3z, a3w);
    }
    __syncthreads();

    // ---- E: updin -> S2 ----
    {
        int i = lane127, h = i >> 5, d = i & 31;
        float acc[4] = {0.f, 0.f, 0.f, 0.f};
        for (int jj = 0; jj < 32; ++jj) {
            float4 w = vp4[jj * DIMF + i];
#pragma unroll
            for (int cc = 0; cc < 4; ++cc) {
                float4 pv = *(const float4*)&S1[cg + cc][h * DIMF + jj * 4];
                acc[cc] += w.x * pv.x + w.y * pv.y + w.z * pv.z + w.w * pv.w;
            }
        }
        __syncthreads();
#pragma unroll
        for (int cc = 0; cc < 4; ++cc) S2[cg + cc][d * NH + h] = acc[cc];
    }
    __syncthreads();

    // ---- F: upd = Wo @ updin + bo -> S3 ----
    {
        int i = lane127;
        float acc[4] = {0.f, 0.f, 0.f, 0.f};
        for (int jj = 0; jj < 32; ++jj) {
            float4 w = op4[jj * DIMF + i];
#pragma unroll
            for (int cc = 0; cc < 4; ++cc) {
                float4 x = *(const float4*)&S2[cg + cc][jj * 4];
                acc[cc] += w.x * x.x + w.y * x.y + w.z * x.z + w.w * x.w;
            }
        }
        float b = bo[i];
        __syncthreads();
#pragma unroll
        for (int cc = 0; cc < 4; ++cc) S3[cg + cc][i] = acc[cc] + b;
    }
    __syncthreads();

    // ---- G: LN1 + residual -> cf2 (fp32) and cf2h (f16, S2 region, swizzled) ----
    // S2 is dead after F's reads (barrier above), so writing cf2h here is safe.
    {
        int i4 = k32 * 4;
        float4 u = *(const float4*)&S3[c8][i4];
        float s = ((u.x + u.y) + u.z) + u.w;
        for (int o = 16; o; o >>= 1) s += __shfl_xor(s, o, 32);
        float mu = s * (1.0f / DIMF);
        float d0 = u.x - mu, d1 = u.y - mu, d2 = u.z - mu, d3 = u.w - mu;
        float vs = ((d0 * d0 + d1 * d1) + d2 * d2) + d3 * d3;
        for (int o = 16; o; o >>= 1) vs += __shfl_xor(vs, o, 32);
        float rs = 1.0f / sqrtf(vs * (1.0f / DIMF) + 1e-5f);
        float4 g = *(const float4*)&g1[i4];
        float4 b = *(const float4*)&be1[i4];
        float4 base = *(const float4*)&cf[c8][i4];
        float4 r;
        r.x = base.x + d0 * rs * g.x + b.x;
        r.y = base.y + d1 * rs * g.y + b.y;
        r.z = base.z + d2 * rs * g.z + b.z;
        r.w = base.w + d3 * rs * g.w + b.w;
        *(float4*)&cf2[c8][i4] = r;
        // f16 copy [16 rows][128], byte = row*256+col*2, XOR-swizzled by row.
        // Rows 8-15 stay as garbage; MFMA rows are independent, outputs discarded.
        {
            int byteoff = (c8 * 256 + i4 * 2) ^ ((c8 & 7) << 4);
            f16x4 hv = {(_Float16)r.x, (_Float16)r.y, (_Float16)r.z, (_Float16)r.w};
            *(f16x4*)(smem + 24576 + byteoff) = hv;
        }
    }
    __syncthreads();

    // ---- H: FFN1 via f16 MFMA: hid[16x512] = relu(cf2h @ W1^T + b1) -> S1 (f16) ----
    // A-frag: lane holds row=lane&15, k=(lane>>4)*8+j. D: col=lane&15, row=(lane>>4)*4+r.
    {
        int lane = t & 63, w = t >> 6;
        int la = lane & 15, kg = lane >> 4;
        f16x8 afr[4];
#pragma unroll
        for (int ks = 0; ks < 4; ++ks) {
            int byteoff = (la * 256 + ks * 64 + kg * 16) ^ ((la & 7) << 4);
            afr[ks] = *(const f16x8*)(smem + 24576 + byteoff);
        }
#pragma unroll
        for (int nt0 = 0; nt0 < 8; ++nt0) {
            int nt = w * 8 + nt0;
            f32x4 acc = {0.f, 0.f, 0.f, 0.f};
#pragma unroll
            for (int ks = 0; ks < 4; ++ks) {
                f16x8 bfr = w1h[(nt * 4 + ks) * 64 + lane];
                acc = __builtin_amdgcn_mfma_f32_16x16x32_f16(afr[ks], bfr, acc, 0, 0, 0);
            }
            int col = nt * 16 + la;
            float bb = b1f[col];
#pragma unroll
            for (int r = 0; r < 4; ++r) {
                int row = kg * 4 + r;
                float v = fmaxf(acc[r] + bb, 0.f);
                int byteoff = (row * 1024 + col * 2) ^ ((row & 7) << 4);
                *(_Float16*)(smem + 8192 + byteoff) = (_Float16)v;
            }
        }
    }
    __syncthreads();

    // ---- I: FFN2 via f16 MFMA: out[16x128] = hid @ W2^T + b2 -> S3 rows 0..7 ----
    {
        int lane = t & 63, w = t >> 6;
        int la = lane & 15, kg = lane >> 4;
        int nt0 = w * 2, nt1 = w * 2 + 1;
        f32x4 acc0 = {0.f, 0.f, 0.f, 0.f}, acc1 = {0.f, 0.f, 0.f, 0.f};
#pragma unroll
        for (int ks = 0; ks < 16; ++ks) {
            int byteoff = (la * 1024 + ks * 64 + kg * 16) ^ ((la & 7) << 4);
            f16x8 afr = *(const f16x8*)(smem + 8192 + byteoff);
            f16x8 b0 = w2h[(nt0 * 16 + ks) * 64 + lane];
            f16x8 b1v = w2h[(nt1 * 16 + ks) * 64 + lane];
            acc0 = __builtin_amdgcn_mfma_f32_16x16x32_f16(afr, b0, acc0, 0, 0, 0);
            acc1 = __builtin_amdgcn_mfma_f32_16x16x32_f16(afr, b1v, acc1, 0, 0, 0);
        }
        if (lane < 32) {  // rows 0..7 only
            float bb0 = b2f[nt0 * 16 + la];
            float bb1 = b2f[nt1 * 16 + la];
#pragma unroll
            for (int r = 0; r < 4; ++r) {
                int row = kg * 4 + r;
                S3[row][nt0 * 16 + la] = acc0[r] + bb0;
                S3[row][nt1 * 16 + la] = acc1[r] + bb1;
            }
        }
    }
    __syncthreads();

    // ---- J: LN2 + residual -> cfin ----
    {
        int i4 = k32 * 4;
        float4 u = *(const float4*)&S3[c8][i4];
        float s = ((u.x + u.y) + u.z) + u.w;
        for (int o = 16; o; o >>= 1) s += __shfl_xor(s, o, 32);
        float mu = s * (1.0f / DIMF);
        float d0 = u.x - mu, d1 = u.y - mu, d2 = u.z - mu, d3 = u.w - mu;
        float vs = ((d0 * d0 + d1 * d1) + d2 * d2) + d3 * d3;
        for (int o = 16; o; o >>= 1) vs += __shfl_xor(vs, o, 32);
        float rs = 1.0f / sqrtf(vs * (1.0f / DIMF) + 1e-5f);
        float4 g = *(const float4*)&g2[i4];
        float4 b = *(const float4*)&be2[i4];
        float4 base = *(const float4*)&cf2[c8][i4];
        float4 r;
        r.x = base.x + d0 * rs * g.x + b.x;
        r.y = base.y + d1 * rs * g.y + b.y;
        r.z = base.z + d2 * rs * g.z + b.z;
        r.w = base.w + d3 * rs * g.w + b.w;
        *(float4*)&cfin[(long)(m0 + c8) * DIMF + i4] = r;
    }
}

// ================= kernel 3: out = feats + cfin[bestm] ======================
__global__ __launch_bounds__(256) void out_kernel(const float4* __restrict__ feats4,
                                                  const float* __restrict__ cfin,
                                                  const int* __restrict__ bestm,
                                                  float4* __restrict__ out4, int total) {
    int idx = blockIdx.x * 256 + threadIdx.x;
    if (idx >= total) return;
    int n = idx >> 5, c = idx & 31;
    const float4* cf4 = (const float4*)cfin;
    float4 f = feats4[idx];
    float4 g = cf4[(long)bestm[n] * 32 + c];
    out4[idx] = make_float4(f.x + g.x, f.y + g.y, f.z + g.z, f.w + g.w);
}

extern "C" void kernel_launch(void* const* d_in, const int* in_sizes, int n_in,
                              void* d_out, int out_size, void* d_ws, size_t ws_size,
                              hipStream_t stream) {
    const float* xyz = (const float*)d_in[0];
    const float* feats = (const float*)d_in[1];
    const int* idxc = (const int*)d_in[2];
    const float* Wq = (const float*)d_in[3];
    const float* Wk = (const float*)d_in[4];
    const float* Wv = (const float*)d_in[5];
    const float* Wo = (const float*)d_in[6];
    const float* bo = (const float*)d_in[7];
    const float* g1 = (const float*)d_in[8];
    const float* be1 = (const float*)d_in[9];
    const float* g2 = (const float*)d_in[10];
    const float* be2 = (const float*)d_in[11];
    const float* W1 = (const float*)d_in[12];
    const float* b1f = (const float*)d_in[13];
    const float* W2 = (const float*)d_in[14];
    const float* b2f = (const float*)d_in[15];

    int N = in_sizes[0] / 3;
    int M = in_sizes[2];

    char* ws = (char*)d_ws;
    size_t off = 0;
    float* cfin = (float*)(ws + off); off += (size_t)M * DIMF * 4;
    int* bestm = (int*)(ws + off); off += (size_t)N * 4;
    float4* qp4 = (float4*)(ws + off); off += (size_t)DIMF * DIMF * 4;
    float4* vp4 = (float4*)(ws + off); off += (size_t)DIMF * DIMF * 4;
    float4* op4 = (float4*)(ws + off); off += (size_t)DIMF * DIMF * 4;
    float4* kp4 = (float4*)(ws + off); off += (size_t)DIMF * DIMF * 4;
    f16x8* w1h = (f16x8*)(ws + off); off += (size_t)8192 * 16;
    f16x8* w2h = (f16x8*)(ws + off); off += (size_t)8192 * 16;
    float4* xyz4 = (float4*)(ws + off); off += (size_t)N * 16;
    float4* cds4 = (float4*)(ws + off); off += (size_t)M * 16;
    (void)ws_size; (void)n_in; (void)out_size;

    pack_kernel<<<PACK_BLOCKS, 256, 0, stream>>>(
        xyz, idxc, Wq, Wv, Wo, W1, W2, Wk,
        qp4, vp4, op4, kp4, w1h, w2h, xyz4, cds4, N, M);
    main_kernel<<<M / CB + N / PPB, 256, 0, stream>>>(
        xyz4, cds4, feats, idxc, qp4, kp4, vp4, op4, bo, g1, be1, g2, be2,
        w1h, b1f, w2h, b2f, cfin, bestm, N, M);
    out_kernel<<<(N * DIMF / 4 + 255) / 256, 256, 0, stream>>>(
        (const float4*)feats, cfin, bestm, (float4*)d_out, N * DIMF / 4);
}